// Round 1
// baseline (2766.094 us; speedup 1.0000x reference)
//
#include <hip/hip_runtime.h>

#define NB 4
#define NN 2048
#define HIDDEN 256
#define NH 8
#define VD 32

__device__ __forceinline__ float gelu_f(float v) {
    return 0.5f * v * (1.0f + erff(v * 0.7071067811865475f));
}

// scale_h = tan(0.25*pi*(1-1e-7)*(1+sin(r_h)))
__global__ void k_scales(const float* __restrict__ r, float* __restrict__ sc) {
    int h = threadIdx.x;
    if (h < NH) {
        const float c = (float)(0.25 * 3.141592653589793 * (1.0 - 1e-7));
        sc[h] = tanf(c * (1.0f + sinf(r[h])));
    }
}

// h[b,n,c] = gelu(sum_i x[b,n,i]*w[i,c] + b[c]),  IN_C=3
__global__ void k_encode(const float* __restrict__ x, const float* __restrict__ w,
                         const float* __restrict__ b, float* __restrict__ out) {
    int id = blockIdx.x * 256 + threadIdx.x;
    int c = id & 255, rn = id >> 8;
    float acc = b[c];
    acc += x[rn * 3 + 0] * w[c] + x[rn * 3 + 1] * w[256 + c] + x[rn * 3 + 2] * w[512 + c];
    out[id] = gelu_f(acc);
}

// w [H,HID,V] -> W2T [HID, H*V]  (col = h*32+k)
__global__ void k_wt(const float* __restrict__ w, float* __restrict__ o) {
    int id = blockIdx.x * 256 + threadIdx.x;  // 65536 total
    int c = id >> 8, col = id & 255;
    int h = col >> 5, k = col & 31;
    o[id] = w[h * (HIDDEN * VD) + c * VD + k];
}

// Per row of m: k-th smallest (radix select), row min, per-head softmax denom.
__global__ __launch_bounds__(256) void k_thrsel(const float* __restrict__ m,
        const float* __restrict__ sc, float* __restrict__ thr,
        float* __restrict__ mmin, float* __restrict__ invD, int kcount)
{
    __shared__ float rowf[NN];
    __shared__ unsigned hist[256];
    __shared__ float red[256];
    __shared__ unsigned s_bin, s_below;
    const int row = blockIdx.x, t = threadIdx.x;
    const float* mr = m + (size_t)row * NN;

    float lmin = 3.4e38f;
    for (int i = t; i < NN; i += 256) { float v = mr[i]; rowf[i] = v; lmin = fminf(lmin, v); }
    red[t] = lmin; __syncthreads();
    for (int s = 128; s > 0; s >>= 1) { if (t < s) red[t] = fminf(red[t], red[t + s]); __syncthreads(); }
    const float rmin = red[0];
    __syncthreads();

    // radix select k-th smallest on order-preserving uint transform
    unsigned prefix = 0; int want = kcount;
    const unsigned hmasks[4] = {0u, 0xFF000000u, 0xFFFF0000u, 0xFFFFFF00u};
    for (int pass = 0; pass < 4; ++pass) {
        const int shift = 24 - 8 * pass;
        hist[t] = 0; __syncthreads();
        const unsigned hm = hmasks[pass];
        for (int i = t; i < NN; i += 256) {
            unsigned u = __float_as_uint(rowf[i]);
            u ^= (u & 0x80000000u) ? 0xFFFFFFFFu : 0x80000000u;
            if ((u & hm) == (prefix & hm))
                atomicAdd(&hist[(u >> shift) & 255u], 1u);
        }
        __syncthreads();
        // Hillis-Steele inclusive scan over 256 bins
        for (int off = 1; off < 256; off <<= 1) {
            unsigned cur = hist[t];
            unsigned add = (t >= off) ? hist[t - off] : 0u;
            __syncthreads();
            hist[t] = cur + add;
            __syncthreads();
        }
        unsigned incl = hist[t];
        unsigned below = (t == 0) ? 0u : hist[t - 1];
        if (incl >= (unsigned)want && below < (unsigned)want) { s_bin = (unsigned)t; s_below = below; }
        __syncthreads();
        want -= (int)s_below;
        prefix |= (s_bin << shift);
        __syncthreads();
    }
    unsigned ku = prefix;
    ku = (ku & 0x80000000u) ? (ku & 0x7FFFFFFFu) : ~ku;
    const float tf = __uint_as_float(ku);

    // denominators: D[h] = sum_{m<=tf} exp(-scale_h*(m - rmin))
    float sch[NH];
#pragma unroll
    for (int h = 0; h < NH; h++) sch[h] = sc[h];
    float lacc[NH];
#pragma unroll
    for (int h = 0; h < NH; h++) lacc[h] = 0.f;
    for (int i = t; i < NN; i += 256) {
        float v = rowf[i];
        if (v <= tf) {
            float d = v - rmin;
#pragma unroll
            for (int h = 0; h < NH; h++) lacc[h] += expf(-sch[h] * d);
        }
    }
#pragma unroll
    for (int h = 0; h < NH; h++) {
        red[t] = lacc[h]; __syncthreads();
        for (int s = 128; s > 0; s >>= 1) { if (t < s) red[t] += red[t + s]; __syncthreads(); }
        if (t == 0) invD[h * NN + row] = 1.0f / red[0];
        __syncthreads();
    }
    if (t == 0) { thr[row] = tf; mmin[row] = rmin; }
}

// C[r,c] = act( A[r,:]@W[:,c] + bias[c] + add[r,c] )   M=8192, K=256, Ncol=256
__global__ __launch_bounds__(256) void k_gemm(const float* __restrict__ A,
        const float* __restrict__ Wm, const float* __restrict__ bias,
        const float* __restrict__ addsrc, float* __restrict__ Cm, int act)
{
    __shared__ float AsT[64 * 68];  // [kk][row], padded
    __shared__ float Ws[64 * 68];   // [kk][col], padded
    const int r0 = blockIdx.x * 64;
    const int c0 = blockIdx.y * 64;
    const int t = threadIdx.x;
    const int ty = t >> 4, tx = t & 15;
    float acc[4][4] = {};
    for (int k0 = 0; k0 < 256; k0 += 64) {
        __syncthreads();
#pragma unroll
        for (int l = 0; l < 16; l++) {
            int lin = l * 256 + t;
            int rr = lin >> 6, kk = lin & 63;
            AsT[kk * 68 + rr] = A[(size_t)(r0 + rr) * 256 + k0 + kk];
            Ws[rr * 68 + kk]  = Wm[(size_t)(k0 + rr) * 256 + c0 + kk];
        }
        __syncthreads();
#pragma unroll 8
        for (int kk = 0; kk < 64; kk++) {
            const float4 a4 = *(const float4*)&AsT[kk * 68 + ty * 4];
            const float4 w4 = *(const float4*)&Ws[kk * 68 + tx * 4];
            float av[4] = {a4.x, a4.y, a4.z, a4.w};
            float wv[4] = {w4.x, w4.y, w4.z, w4.w};
#pragma unroll
            for (int q = 0; q < 4; q++)
#pragma unroll
                for (int p = 0; p < 4; p++)
                    acc[q][p] = fmaf(av[q], wv[p], acc[q][p]);
        }
    }
#pragma unroll
    for (int q = 0; q < 4; q++) {
        int r = r0 + ty * 4 + q;
#pragma unroll
        for (int p = 0; p < 4; p++) {
            int c = c0 + tx * 4 + p;
            float v = acc[q][p];
            if (bias) v += bias[c];
            if (addsrc) v += addsrc[(size_t)r * 256 + c];
            if (act) v = gelu_f(v);
            Cm[(size_t)r * 256 + c] = v;
        }
    }
}

// out[b, i, h*32+k] = gelu( invD[h,i] * sum_j e(m[i,j]) * V2[b, j, h*32+k] )
// e = (m<=thr_i) * exp(-scale_h*(m - mmin_i))
// grid: blockIdx.x = head*64 + itile (TI=32); 128 cols = (b,k)
__global__ __launch_bounds__(256) void k_attapply(const float* __restrict__ m,
        const float* __restrict__ v2, const float* __restrict__ sc,
        const float* __restrict__ thr, const float* __restrict__ mmin,
        const float* __restrict__ invD, float* __restrict__ dst)
{
    __shared__ float eT[64 * 36];    // [jj][ii], TI=32, padded to 36
    __shared__ float Vs[64 * 128];   // [jj][col]
    const int head = blockIdx.x >> 6;
    const int i0 = (blockIdx.x & 63) * 32;
    const int t = threadIdx.x;
    const int ty = t >> 5, tx = t & 31;   // rows ty*4.., cols tx*4..
    const float scale = sc[head];
    float acc[4][4] = {};
    for (int j0 = 0; j0 < NN; j0 += 64) {
        __syncthreads();
#pragma unroll
        for (int l = 0; l < 8; l++) {
            int lin = l * 256 + t;
            int ii = lin >> 6, jj = lin & 63;
            int gi = i0 + ii, gj = j0 + jj;
            float mv = m[(size_t)gi * NN + gj];
            float e = 0.f;
            if (mv <= thr[gi]) e = expf(-scale * (mv - mmin[gi]));
            eT[jj * 36 + ii] = e;
        }
#pragma unroll
        for (int l = 0; l < 32; l++) {
            int lin = l * 256 + t;
            int jj = lin >> 7, col = lin & 127;
            int bb = col >> 5, kk2 = col & 31;
            Vs[jj * 128 + col] = v2[(((size_t)bb * NN) + (j0 + jj)) * HIDDEN + head * VD + kk2];
        }
        __syncthreads();
#pragma unroll 8
        for (int jj = 0; jj < 64; jj++) {
            const float4 e4 = *(const float4*)&eT[jj * 36 + ty * 4];
            const float4 v4 = *(const float4*)&Vs[jj * 128 + tx * 4];
            float ev[4] = {e4.x, e4.y, e4.z, e4.w};
            float vv[4] = {v4.x, v4.y, v4.z, v4.w};
#pragma unroll
            for (int q = 0; q < 4; q++)
#pragma unroll
                for (int p = 0; p < 4; p++)
                    acc[q][p] = fmaf(ev[q], vv[p], acc[q][p]);
        }
    }
#pragma unroll
    for (int q = 0; q < 4; q++) {
        const int gi = i0 + ty * 4 + q;
        const float idv = invD[head * NN + gi];
#pragma unroll
        for (int p = 0; p < 4; p++) {
            const int col = tx * 4 + p;
            const int bb = col >> 5, kk2 = col & 31;
            dst[(((size_t)bb * NN) + gi) * HIDDEN + head * VD + kk2] = gelu_f(acc[q][p] * idv);
        }
    }
}

// out[row] = sum_c A[row,c]*w[c] + b   (one wave per row)
__global__ void k_decode(const float* __restrict__ a, const float* __restrict__ w,
                         const float* __restrict__ b, float* __restrict__ out) {
    int gid = blockIdx.x * 256 + threadIdx.x;
    int row = gid >> 6, lane = threadIdx.x & 63;
    const float* ar = a + (size_t)row * HIDDEN;
    float s = ar[lane] * w[lane] + ar[lane + 64] * w[lane + 64]
            + ar[lane + 128] * w[lane + 128] + ar[lane + 192] * w[lane + 192];
    for (int off = 32; off > 0; off >>= 1) s += __shfl_down(s, off);
    if (lane == 0) out[row] = s + b[0];
}

extern "C" void kernel_launch(void* const* d_in, const int* in_sizes, int n_in,
                              void* d_out, int out_size, void* d_ws, size_t ws_size,
                              hipStream_t stream)
{
    (void)in_sizes; (void)n_in; (void)out_size; (void)ws_size;
    const float* x      = (const float*)d_in[0];
    const float* m0     = (const float*)d_in[1];
    const float* m1     = (const float*)d_in[2];
    const float* m2     = (const float*)d_in[3];
    const float* m3     = (const float*)d_in[4];
    const float* en_w   = (const float*)d_in[5];
    const float* en_b   = (const float*)d_in[6];
    const float* down_r = (const float*)d_in[7];
    const float* down_w = (const float*)d_in[8];
    const float* pa0_r  = (const float*)d_in[9];
    const float* pa0_w  = (const float*)d_in[10];
    const float* pa1_r  = (const float*)d_in[11];
    const float* pa1_w  = (const float*)d_in[12];
    const float* mlp0_w1= (const float*)d_in[13];
    const float* mlp0_b1= (const float*)d_in[14];
    const float* mlp0_w2= (const float*)d_in[15];
    const float* mlp0_b2= (const float*)d_in[16];
    const float* w0_w   = (const float*)d_in[17];
    const float* w0_b   = (const float*)d_in[18];
    const float* mlp1_w1= (const float*)d_in[19];
    const float* mlp1_b1= (const float*)d_in[20];
    const float* mlp1_w2= (const float*)d_in[21];
    const float* mlp1_b2= (const float*)d_in[22];
    const float* w1_w   = (const float*)d_in[23];
    const float* w1_b   = (const float*)d_in[24];
    const float* up_r   = (const float*)d_in[25];
    const float* up_w   = (const float*)d_in[26];
    const float* de1_w  = (const float*)d_in[27];
    const float* de1_b  = (const float*)d_in[28];
    const float* de2_w  = (const float*)d_in[29];
    const float* de2_b  = (const float*)d_in[30];
    float* out = (float*)d_out;

    // workspace layout (floats): 4 x 8MB activation buffers + small arrays (~34 MB)
    float* WS = (float*)d_ws;
    const size_t SZ = (size_t)NB * NN * HIDDEN;
    float* Hb  = WS;
    float* Ab  = Hb + SZ;
    float* Vb  = Ab + SZ;
    float* T1  = Vb + SZ;
    float* W2T = T1 + SZ;       // 65536
    float* SC  = W2T + 65536;   // 16
    float* THR = SC + 16;       // 2048
    float* MMIN= THR + NN;      // 2048
    float* INVD= MMIN + NN;     // H*N
    float* T3  = Vb;            // alias: value buffer is dead once attapply is done

    auto posatt = [&](const float* src, float* dst2, const float* md,
                      const float* r, const float* w, int kc) {
        hipLaunchKernelGGL(k_scales, dim3(1), dim3(64), 0, stream, r, SC);
        hipLaunchKernelGGL(k_thrsel, dim3(NN), dim3(256), 0, stream, md, SC, THR, MMIN, INVD, kc);
        hipLaunchKernelGGL(k_wt, dim3(256), dim3(256), 0, stream, w, W2T);
        hipLaunchKernelGGL(k_gemm, dim3(128, 4), dim3(256), 0, stream,
                           src, W2T, (const float*)nullptr, (const float*)nullptr, Vb, 0);
        hipLaunchKernelGGL(k_attapply, dim3(512), dim3(256), 0, stream,
                           md, Vb, SC, THR, MMIN, INVD, dst2);
    };

    float* curH = Hb; float* oth = Ab;
    hipLaunchKernelGGL(k_encode, dim3(8192), dim3(256), 0, stream, x, en_w, en_b, curH);

    // down: locality 50 -> k=1024
    posatt(curH, oth, m0, down_r, down_w, 1024);
    { float* tmp = curH; curH = oth; oth = tmp; }

    // block 0: PA uses locality 50 -> k=1024
    posatt(curH, oth, m1, pa0_r, pa0_w, 1024);
    hipLaunchKernelGGL(k_gemm, dim3(128, 4), dim3(256), 0, stream,
                       curH, w0_w, w0_b, (const float*)nullptr, T3, 0);
    hipLaunchKernelGGL(k_gemm, dim3(128, 4), dim3(256), 0, stream,
                       oth, mlp0_w1, mlp0_b1, (const float*)nullptr, T1, 1);
    hipLaunchKernelGGL(k_gemm, dim3(128, 4), dim3(256), 0, stream,
                       T1, mlp0_w2, mlp0_b2, (const float*)T3, oth, 1);
    { float* tmp = curH; curH = oth; oth = tmp; }

    // block 1: PA uses locality 30 -> k = floor(0.3f*2047)+1 = 615
    posatt(curH, oth, m2, pa1_r, pa1_w, 615);
    hipLaunchKernelGGL(k_gemm, dim3(128, 4), dim3(256), 0, stream,
                       curH, w1_w, w1_b, (const float*)nullptr, T3, 0);
    hipLaunchKernelGGL(k_gemm, dim3(128, 4), dim3(256), 0, stream,
                       oth, mlp1_w1, mlp1_b1, (const float*)nullptr, T1, 1);
    hipLaunchKernelGGL(k_gemm, dim3(128, 4), dim3(256), 0, stream,
                       T1, mlp1_w2, mlp1_b2, (const float*)T3, oth, 1);
    { float* tmp = curH; curH = oth; oth = tmp; }

    // up: locality 80 -> k = floor(0.8f*2047)+1 = 1638
    posatt(curH, oth, m3, up_r, up_w, 1638);
    { float* tmp = curH; curH = oth; oth = tmp; }

    hipLaunchKernelGGL(k_gemm, dim3(128, 4), dim3(256), 0, stream,
                       curH, de1_w, de1_b, (const float*)nullptr, T1, 1);
    hipLaunchKernelGGL(k_decode, dim3(2048), dim3(256), 0, stream, T1, de2_w, de2_b, out);
}

// Round 2
// 1456.576 us; speedup vs baseline: 1.8990x; 1.8990x over previous
//
#include <hip/hip_runtime.h>

#define NB 4
#define NN 2048
#define HIDDEN 256
#define NH 8
#define VD 32
#define TJ 64

typedef float f4 __attribute__((ext_vector_type(4)));

__device__ __forceinline__ float gelu_f(float v) {
    return 0.5f * v * (1.0f + erff(v * 0.7071067811865475f));
}

// scale_h = tan(0.25*pi*(1-1e-7)*(1+sin(r_h)))
__global__ void k_scales(const float* __restrict__ r, float* __restrict__ sc) {
    int h = threadIdx.x;
    if (h < NH) {
        const float c = (float)(0.25 * 3.141592653589793 * (1.0 - 1e-7));
        sc[h] = tanf(c * (1.0f + sinf(r[h])));
    }
}

// h[b,n,c] = gelu(sum_i x[b,n,i]*w[i,c] + b[c]),  IN_C=3
__global__ void k_encode(const float* __restrict__ x, const float* __restrict__ w,
                         const float* __restrict__ b, float* __restrict__ out) {
    int id = blockIdx.x * 256 + threadIdx.x;
    int c = id & 255, rn = id >> 8;
    float acc = b[c];
    acc += x[rn * 3 + 0] * w[c] + x[rn * 3 + 1] * w[256 + c] + x[rn * 3 + 2] * w[512 + c];
    out[id] = gelu_f(acc);
}

// w [H,HID,V] -> W2T [HID, H*V]  (col = h*32+k)
__global__ void k_wt(const float* __restrict__ w, float* __restrict__ o) {
    int id = blockIdx.x * 256 + threadIdx.x;  // 65536 total
    int c = id >> 8, col = id & 255;
    int h = col >> 5, k = col & 31;
    o[id] = w[h * (HIDDEN * VD) + c * VD + k];
}

// Per row of m: k-th smallest (radix select), row min, per-head softmax denom.
__global__ __launch_bounds__(256) void k_thrsel(const float* __restrict__ m,
        const float* __restrict__ sc, float* __restrict__ thr,
        float* __restrict__ mmin, float* __restrict__ invD, int kcount)
{
    __shared__ float rowf[NN];
    __shared__ unsigned hist[256];
    __shared__ float red[256];
    __shared__ unsigned s_bin, s_below;
    const int row = blockIdx.x, t = threadIdx.x;
    const float* mr = m + (size_t)row * NN;

    float lmin = 3.4e38f;
    for (int i = t; i < NN; i += 256) { float v = mr[i]; rowf[i] = v; lmin = fminf(lmin, v); }
    red[t] = lmin; __syncthreads();
    for (int s = 128; s > 0; s >>= 1) { if (t < s) red[t] = fminf(red[t], red[t + s]); __syncthreads(); }
    const float rmin = red[0];
    __syncthreads();

    // radix select k-th smallest on order-preserving uint transform
    unsigned prefix = 0; int want = kcount;
    const unsigned hmasks[4] = {0u, 0xFF000000u, 0xFFFF0000u, 0xFFFFFF00u};
    for (int pass = 0; pass < 4; ++pass) {
        const int shift = 24 - 8 * pass;
        hist[t] = 0; __syncthreads();
        const unsigned hm = hmasks[pass];
        for (int i = t; i < NN; i += 256) {
            unsigned u = __float_as_uint(rowf[i]);
            u ^= (u & 0x80000000u) ? 0xFFFFFFFFu : 0x80000000u;
            if ((u & hm) == (prefix & hm))
                atomicAdd(&hist[(u >> shift) & 255u], 1u);
        }
        __syncthreads();
        for (int off = 1; off < 256; off <<= 1) {
            unsigned cur = hist[t];
            unsigned add = (t >= off) ? hist[t - off] : 0u;
            __syncthreads();
            hist[t] = cur + add;
            __syncthreads();
        }
        unsigned incl = hist[t];
        unsigned below = (t == 0) ? 0u : hist[t - 1];
        if (incl >= (unsigned)want && below < (unsigned)want) { s_bin = (unsigned)t; s_below = below; }
        __syncthreads();
        want -= (int)s_below;
        prefix |= (s_bin << shift);
        __syncthreads();
    }
    unsigned ku = prefix;
    ku = (ku & 0x80000000u) ? (ku & 0x7FFFFFFFu) : ~ku;
    const float tf = __uint_as_float(ku);

    float sch[NH];
#pragma unroll
    for (int h = 0; h < NH; h++) sch[h] = sc[h];
    float lacc[NH];
#pragma unroll
    for (int h = 0; h < NH; h++) lacc[h] = 0.f;
    for (int i = t; i < NN; i += 256) {
        float v = rowf[i];
        if (v <= tf) {
            float d = v - rmin;
#pragma unroll
            for (int h = 0; h < NH; h++) lacc[h] += expf(-sch[h] * d);
        }
    }
#pragma unroll
    for (int h = 0; h < NH; h++) {
        red[t] = lacc[h]; __syncthreads();
        for (int s = 128; s > 0; s >>= 1) { if (t < s) red[t] += red[t + s]; __syncthreads(); }
        if (t == 0) invD[h * NN + row] = 1.0f / red[0];
        __syncthreads();
    }
    if (t == 0) { thr[row] = tf; mmin[row] = rmin; }
}

// C[r,c] = act( A[r,:]@W[:,c] + bias[c] + add[r,c] )   M=8192, K=256, Ncol=256
__global__ __launch_bounds__(256) void k_gemm(const float* __restrict__ A,
        const float* __restrict__ Wm, const float* __restrict__ bias,
        const float* __restrict__ addsrc, float* __restrict__ Cm, int act)
{
    __shared__ float AsT[64 * 68];  // [kk][row], padded
    __shared__ float Ws[64 * 68];   // [kk][col], padded
    const int r0 = blockIdx.x * 64;
    const int c0 = blockIdx.y * 64;
    const int t = threadIdx.x;
    const int ty = t >> 4, tx = t & 15;
    float acc[4][4] = {};
    for (int k0 = 0; k0 < 256; k0 += 64) {
        __syncthreads();
#pragma unroll
        for (int l = 0; l < 16; l++) {
            int lin = l * 256 + t;
            int rr = lin >> 6, kk = lin & 63;
            AsT[kk * 68 + rr] = A[(size_t)(r0 + rr) * 256 + k0 + kk];
            Ws[rr * 68 + kk]  = Wm[(size_t)(k0 + rr) * 256 + c0 + kk];
        }
        __syncthreads();
#pragma unroll 8
        for (int kk = 0; kk < 64; kk++) {
            const float4 a4 = *(const float4*)&AsT[kk * 68 + ty * 4];
            const float4 w4 = *(const float4*)&Ws[kk * 68 + tx * 4];
            float av[4] = {a4.x, a4.y, a4.z, a4.w};
            float wv[4] = {w4.x, w4.y, w4.z, w4.w};
#pragma unroll
            for (int q = 0; q < 4; q++)
#pragma unroll
                for (int p = 0; p < 4; p++)
                    acc[q][p] = fmaf(av[q], wv[p], acc[q][p]);
        }
    }
#pragma unroll
    for (int q = 0; q < 4; q++) {
        int r = r0 + ty * 4 + q;
#pragma unroll
        for (int p = 0; p < 4; p++) {
            int c = c0 + tx * 4 + p;
            float v = acc[q][p];
            if (bias) v += bias[c];
            if (addsrc) v += addsrc[(size_t)r * 256 + c];
            if (act) v = gelu_f(v);
            Cm[(size_t)r * 256 + c] = v;
        }
    }
}

// Partial att-apply: P[b,i,h*32+k] = sum_{j in half} e(m[i,j]) * V2[b,j,h*32+k]
// e = (m<=thr_i) * exp(-scale_h*(m - mmin_i))
// grid: (head*32 + itile, jsplit), 128 threads, TI=64 rows, acc 8x8/thread.
__global__ __launch_bounds__(128, 1) void k_attapply2(
    const float* __restrict__ m, const float* __restrict__ v2,
    const float* __restrict__ sc, const float* __restrict__ thr,
    const float* __restrict__ mmin, float* __restrict__ P0, float* __restrict__ P1)
{
    __shared__ float Es[TJ * 68];     // [jj][ii] transposed, stride 68
    __shared__ float Vs[TJ * 128];    // [jj][col]
    const int head = blockIdx.x >> 5;
    const int i0 = (blockIdx.x & 31) * 64;
    const int jbase = blockIdx.y * (NN / 2);
    float* __restrict__ P = (blockIdx.y == 0) ? P0 : P1;
    const int t = threadIdx.x;          // 0..127
    const int tx = t & 15, ty = t >> 4; // cols tx*8.., rows ty*8..
    const float scale = sc[head];

    // rows this thread stages for the e-tile: ii = 8*l + ty
    float thr_r[8], mmn_r[8];
#pragma unroll
    for (int l = 0; l < 8; l++) {
        thr_r[l] = thr[i0 + 8 * l + ty];
        mmn_r[l] = mmin[i0 + 8 * l + ty];
    }

    float acc[8][8];
#pragma unroll
    for (int q = 0; q < 8; q++)
#pragma unroll
        for (int p = 0; p < 8; p++) acc[q][p] = 0.f;

    for (int s = 0; s < (NN / 2) / TJ; s++) {
        const int j0 = jbase + s * TJ;
        __syncthreads();
        // stage E (transposed): thread reads m[ii][jj0..3] as float4, writes scalars
#pragma unroll
        for (int l = 0; l < 8; l++) {
            const int ii = 8 * l + ty;
            f4 mv = *(const f4*)&m[(size_t)(i0 + ii) * NN + j0 + tx * 4];
            const float tf = thr_r[l], mn = mmn_r[l];
#pragma unroll
            for (int d = 0; d < 4; d++) {
                float e = 0.f;
                if (mv[d] <= tf) e = expf(-scale * (mv[d] - mn));
                Es[(tx * 4 + d) * 68 + ii] = e;
            }
        }
        // stage V: coalesced float4
#pragma unroll
        for (int l = 0; l < 16; l++) {
            const int f = l * 128 + t;
            const int jj = f >> 5, c4 = f & 31;
            const int col = c4 * 4, bb = col >> 5, kk = col & 31;
            *(f4*)&Vs[jj * 128 + col] =
                *(const f4*)&v2[(((size_t)bb * NN) + j0 + jj) * HIDDEN + head * VD + kk];
        }
        __syncthreads();
        // compute: per 4-jj chunk: 8 e-loads (broadcast) + 8 v-loads, 256 FMA
        for (int jc = 0; jc < TJ; jc += 4) {
            f4 evlo[4], evhi[4], vvlo[4], vvhi[4];
#pragma unroll
            for (int d = 0; d < 4; d++) {
                evlo[d] = *(const f4*)&Es[(jc + d) * 68 + ty * 8];
                evhi[d] = *(const f4*)&Es[(jc + d) * 68 + ty * 8 + 4];
                vvlo[d] = *(const f4*)&Vs[(jc + d) * 128 + tx * 8];
                vvhi[d] = *(const f4*)&Vs[(jc + d) * 128 + tx * 8 + 4];
            }
#pragma unroll
            for (int d = 0; d < 4; d++) {
#pragma unroll
                for (int q = 0; q < 8; q++) {
                    const float e = (q < 4) ? evlo[d][q] : evhi[d][q - 4];
#pragma unroll
                    for (int p = 0; p < 4; p++) {
                        acc[q][p]     = fmaf(e, vvlo[d][p], acc[q][p]);
                        acc[q][p + 4] = fmaf(e, vvhi[d][p], acc[q][p + 4]);
                    }
                }
            }
        }
    }
    // epilogue: raw partial sums (invD/gelu applied in combine)
#pragma unroll
    for (int q = 0; q < 8; q++) {
        const int gi = i0 + ty * 8 + q;
#pragma unroll
        for (int h4 = 0; h4 < 2; h4++) {
            const int col = tx * 8 + h4 * 4;
            const int bb = col >> 5, kk = col & 31;
            f4 st;
#pragma unroll
            for (int p = 0; p < 4; p++) st[p] = acc[q][h4 * 4 + p];
            *(f4*)&P[(((size_t)bb * NN) + gi) * HIDDEN + head * VD + kk] = st;
        }
    }
}

// io[idx] = gelu((io[idx] + p1[idx]) * invD[h,i])
__global__ __launch_bounds__(256) void k_attcombine(const float* __restrict__ p1,
        const float* __restrict__ invD, float* __restrict__ io)
{
    int gid = blockIdx.x * 256 + threadIdx.x;
    int idx = gid * 4;
    int hid = idx & (HIDDEN - 1);
    int i = (idx >> 8) & (NN - 1);
    float sD = invD[(hid >> 5) * NN + i];
    f4 a = *(const f4*)&io[idx];
    f4 b = *(const f4*)&p1[idx];
    f4 r;
#pragma unroll
    for (int k = 0; k < 4; k++) r[k] = gelu_f((a[k] + b[k]) * sD);
    *(f4*)&io[idx] = r;
}

// out[row] = sum_c A[row,c]*w[c] + b   (one wave per row)
__global__ void k_decode(const float* __restrict__ a, const float* __restrict__ w,
                         const float* __restrict__ b, float* __restrict__ out) {
    int gid = blockIdx.x * 256 + threadIdx.x;
    int row = gid >> 6, lane = threadIdx.x & 63;
    const float* ar = a + (size_t)row * HIDDEN;
    float s = ar[lane] * w[lane] + ar[lane + 64] * w[lane + 64]
            + ar[lane + 128] * w[lane + 128] + ar[lane + 192] * w[lane + 192];
    for (int off = 32; off > 0; off >>= 1) s += __shfl_down(s, off);
    if (lane == 0) out[row] = s + b[0];
}

extern "C" void kernel_launch(void* const* d_in, const int* in_sizes, int n_in,
                              void* d_out, int out_size, void* d_ws, size_t ws_size,
                              hipStream_t stream)
{
    (void)in_sizes; (void)n_in; (void)out_size; (void)ws_size;
    const float* x      = (const float*)d_in[0];
    const float* m0     = (const float*)d_in[1];
    const float* m1     = (const float*)d_in[2];
    const float* m2     = (const float*)d_in[3];
    const float* m3     = (const float*)d_in[4];
    const float* en_w   = (const float*)d_in[5];
    const float* en_b   = (const float*)d_in[6];
    const float* down_r = (const float*)d_in[7];
    const float* down_w = (const float*)d_in[8];
    const float* pa0_r  = (const float*)d_in[9];
    const float* pa0_w  = (const float*)d_in[10];
    const float* pa1_r  = (const float*)d_in[11];
    const float* pa1_w  = (const float*)d_in[12];
    const float* mlp0_w1= (const float*)d_in[13];
    const float* mlp0_b1= (const float*)d_in[14];
    const float* mlp0_w2= (const float*)d_in[15];
    const float* mlp0_b2= (const float*)d_in[16];
    const float* w0_w   = (const float*)d_in[17];
    const float* w0_b   = (const float*)d_in[18];
    const float* mlp1_w1= (const float*)d_in[19];
    const float* mlp1_b1= (const float*)d_in[20];
    const float* mlp1_w2= (const float*)d_in[21];
    const float* mlp1_b2= (const float*)d_in[22];
    const float* w1_w   = (const float*)d_in[23];
    const float* w1_b   = (const float*)d_in[24];
    const float* up_r   = (const float*)d_in[25];
    const float* up_w   = (const float*)d_in[26];
    const float* de1_w  = (const float*)d_in[27];
    const float* de1_b  = (const float*)d_in[28];
    const float* de2_w  = (const float*)d_in[29];
    const float* de2_b  = (const float*)d_in[30];
    float* out = (float*)d_out;

    float* WS = (float*)d_ws;
    const size_t SZ = (size_t)NB * NN * HIDDEN;
    float* Hb  = WS;
    float* Ab  = Hb + SZ;
    float* Vb  = Ab + SZ;
    float* T1  = Vb + SZ;
    float* W2T = T1 + SZ;       // 65536
    float* SC  = W2T + 65536;   // 16
    float* THR = SC + 16;       // 2048
    float* MMIN= THR + NN;      // 2048
    float* INVD= MMIN + NN;     // H*N
    float* T3  = Vb;            // alias: value buffer dead outside posatt

    auto posatt = [&](const float* src, float* dst2, const float* md,
                      const float* r, const float* w, int kc) {
        hipLaunchKernelGGL(k_scales, dim3(1), dim3(64), 0, stream, r, SC);
        hipLaunchKernelGGL(k_thrsel, dim3(NN), dim3(256), 0, stream, md, SC, THR, MMIN, INVD, kc);
        hipLaunchKernelGGL(k_wt, dim3(256), dim3(256), 0, stream, w, W2T);
        hipLaunchKernelGGL(k_gemm, dim3(128, 4), dim3(256), 0, stream,
                           src, W2T, (const float*)nullptr, (const float*)nullptr, Vb, 0);
        // partial sums: split 0 -> dst2, split 1 -> T1 (both free here)
        hipLaunchKernelGGL(k_attapply2, dim3(256, 2), dim3(128), 0, stream,
                           md, Vb, SC, THR, MMIN, dst2, T1);
        hipLaunchKernelGGL(k_attcombine, dim3((int)(SZ / 4 / 256)), dim3(256), 0, stream,
                           T1, INVD, dst2);
    };

    float* curH = Hb; float* oth = Ab;
    hipLaunchKernelGGL(k_encode, dim3(8192), dim3(256), 0, stream, x, en_w, en_b, curH);

    // down: locality 50 -> k=1024
    posatt(curH, oth, m0, down_r, down_w, 1024);
    { float* tmp = curH; curH = oth; oth = tmp; }

    // block 0: PA uses locality 50 -> k=1024
    posatt(curH, oth, m1, pa0_r, pa0_w, 1024);
    hipLaunchKernelGGL(k_gemm, dim3(128, 4), dim3(256), 0, stream,
                       curH, w0_w, w0_b, (const float*)nullptr, T3, 0);
    hipLaunchKernelGGL(k_gemm, dim3(128, 4), dim3(256), 0, stream,
                       oth, mlp0_w1, mlp0_b1, (const float*)nullptr, T1, 1);
    hipLaunchKernelGGL(k_gemm, dim3(128, 4), dim3(256), 0, stream,
                       T1, mlp0_w2, mlp0_b2, (const float*)T3, oth, 1);
    { float* tmp = curH; curH = oth; oth = tmp; }

    // block 1: PA uses locality 30 -> k=615
    posatt(curH, oth, m2, pa1_r, pa1_w, 615);
    hipLaunchKernelGGL(k_gemm, dim3(128, 4), dim3(256), 0, stream,
                       curH, w1_w, w1_b, (const float*)nullptr, T3, 0);
    hipLaunchKernelGGL(k_gemm, dim3(128, 4), dim3(256), 0, stream,
                       oth, mlp1_w1, mlp1_b1, (const float*)nullptr, T1, 1);
    hipLaunchKernelGGL(k_gemm, dim3(128, 4), dim3(256), 0, stream,
                       T1, mlp1_w2, mlp1_b2, (const float*)T3, oth, 1);
    { float* tmp = curH; curH = oth; oth = tmp; }

    // up: locality 80 -> k=1638
    posatt(curH, oth, m3, up_r, up_w, 1638);
    { float* tmp = curH; curH = oth; oth = tmp; }

    hipLaunchKernelGGL(k_gemm, dim3(128, 4), dim3(256), 0, stream,
                       curH, de1_w, de1_b, (const float*)nullptr, T1, 1);
    hipLaunchKernelGGL(k_decode, dim3(2048), dim3(256), 0, stream, T1, de2_w, de2_b, out);
}

// Round 3
// 1140.125 us; speedup vs baseline: 2.4261x; 1.2776x over previous
//
#include <hip/hip_runtime.h>

#define NB 4
#define NN 2048
#define HIDDEN 256
#define NH 8
#define VD 32
#define TJ 64

typedef float f4 __attribute__((ext_vector_type(4)));

__device__ __forceinline__ float gelu_f(float v) {
    return 0.5f * v * (1.0f + erff(v * 0.7071067811865475f));
}

// scale_h = tan(0.25*pi*(1-1e-7)*(1+sin(r_h)))
__global__ void k_scales(const float* __restrict__ r, float* __restrict__ sc) {
    int h = threadIdx.x;
    if (h < NH) {
        const float c = (float)(0.25 * 3.141592653589793 * (1.0 - 1e-7));
        sc[h] = tanf(c * (1.0f + sinf(r[h])));
    }
}

// h[b,n,c] = gelu(sum_i x[b,n,i]*w[i,c] + b[c]),  IN_C=3
__global__ void k_encode(const float* __restrict__ x, const float* __restrict__ w,
                         const float* __restrict__ b, float* __restrict__ out) {
    int id = blockIdx.x * 256 + threadIdx.x;
    int c = id & 255, rn = id >> 8;
    float acc = b[c];
    acc += x[rn * 3 + 0] * w[c] + x[rn * 3 + 1] * w[256 + c] + x[rn * 3 + 2] * w[512 + c];
    out[id] = gelu_f(acc);
}

// w [H,HID,V] -> W2T [HID, H*V]  (col = h*32+k)
__global__ void k_wt(const float* __restrict__ w, float* __restrict__ o) {
    int id = blockIdx.x * 256 + threadIdx.x;  // 65536 total
    int c = id >> 8, col = id & 255;
    int h = col >> 5, k = col & 31;
    o[id] = w[h * (HIDDEN * VD) + c * VD + k];
}

// Per row of m: k-th smallest (radix select), row min, per-head softmax denom.
__global__ __launch_bounds__(256) void k_thrsel(const float* __restrict__ m,
        const float* __restrict__ sc, float* __restrict__ thr,
        float* __restrict__ mmin, float* __restrict__ invD, int kcount)
{
    __shared__ float rowf[NN];
    __shared__ unsigned hist[256];
    __shared__ float red[256];
    __shared__ unsigned s_bin, s_below;
    const int row = blockIdx.x, t = threadIdx.x;
    const float* mr = m + (size_t)row * NN;

    float lmin = 3.4e38f;
    for (int i = t; i < NN; i += 256) { float v = mr[i]; rowf[i] = v; lmin = fminf(lmin, v); }
    red[t] = lmin; __syncthreads();
    for (int s = 128; s > 0; s >>= 1) { if (t < s) red[t] = fminf(red[t], red[t + s]); __syncthreads(); }
    const float rmin = red[0];
    __syncthreads();

    // radix select k-th smallest on order-preserving uint transform
    unsigned prefix = 0; int want = kcount;
    const unsigned hmasks[4] = {0u, 0xFF000000u, 0xFFFF0000u, 0xFFFFFF00u};
    for (int pass = 0; pass < 4; ++pass) {
        const int shift = 24 - 8 * pass;
        hist[t] = 0; __syncthreads();
        const unsigned hm = hmasks[pass];
        for (int i = t; i < NN; i += 256) {
            unsigned u = __float_as_uint(rowf[i]);
            u ^= (u & 0x80000000u) ? 0xFFFFFFFFu : 0x80000000u;
            if ((u & hm) == (prefix & hm))
                atomicAdd(&hist[(u >> shift) & 255u], 1u);
        }
        __syncthreads();
        for (int off = 1; off < 256; off <<= 1) {
            unsigned cur = hist[t];
            unsigned add = (t >= off) ? hist[t - off] : 0u;
            __syncthreads();
            hist[t] = cur + add;
            __syncthreads();
        }
        unsigned incl = hist[t];
        unsigned below = (t == 0) ? 0u : hist[t - 1];
        if (incl >= (unsigned)want && below < (unsigned)want) { s_bin = (unsigned)t; s_below = below; }
        __syncthreads();
        want -= (int)s_below;
        prefix |= (s_bin << shift);
        __syncthreads();
    }
    unsigned ku = prefix;
    ku = (ku & 0x80000000u) ? (ku & 0x7FFFFFFFu) : ~ku;
    const float tf = __uint_as_float(ku);

    float sch[NH];
#pragma unroll
    for (int h = 0; h < NH; h++) sch[h] = sc[h];
    float lacc[NH];
#pragma unroll
    for (int h = 0; h < NH; h++) lacc[h] = 0.f;
    for (int i = t; i < NN; i += 256) {
        float v = rowf[i];
        if (v <= tf) {
            float d = v - rmin;
#pragma unroll
            for (int h = 0; h < NH; h++) lacc[h] += expf(-sch[h] * d);
        }
    }
#pragma unroll
    for (int h = 0; h < NH; h++) {
        red[t] = lacc[h]; __syncthreads();
        for (int s = 128; s > 0; s >>= 1) { if (t < s) red[t] += red[t + s]; __syncthreads(); }
        if (t == 0) invD[h * NN + row] = 1.0f / red[0];
        __syncthreads();
    }
    if (t == 0) { thr[row] = tf; mmin[row] = rmin; }
}

// C[r,c] = act( A[r,:]@W[:,c] + bias[c] + add[r,c] )   M=8192, K=256, Ncol=256
__global__ __launch_bounds__(256) void k_gemm(const float* __restrict__ A,
        const float* __restrict__ Wm, const float* __restrict__ bias,
        const float* __restrict__ addsrc, float* __restrict__ Cm, int act)
{
    __shared__ float AsT[64 * 68];  // [kk][row], padded
    __shared__ float Ws[64 * 68];   // [kk][col], padded
    const int r0 = blockIdx.x * 64;
    const int c0 = blockIdx.y * 64;
    const int t = threadIdx.x;
    const int ty = t >> 4, tx = t & 15;
    float acc[4][4] = {};
    for (int k0 = 0; k0 < 256; k0 += 64) {
        __syncthreads();
#pragma unroll
        for (int l = 0; l < 16; l++) {
            int lin = l * 256 + t;
            int rr = lin >> 6, kk = lin & 63;
            AsT[kk * 68 + rr] = A[(size_t)(r0 + rr) * 256 + k0 + kk];
            Ws[rr * 68 + kk]  = Wm[(size_t)(k0 + rr) * 256 + c0 + kk];
        }
        __syncthreads();
#pragma unroll 8
        for (int kk = 0; kk < 64; kk++) {
            const float4 a4 = *(const float4*)&AsT[kk * 68 + ty * 4];
            const float4 w4 = *(const float4*)&Ws[kk * 68 + tx * 4];
            float av[4] = {a4.x, a4.y, a4.z, a4.w};
            float wv[4] = {w4.x, w4.y, w4.z, w4.w};
#pragma unroll
            for (int q = 0; q < 4; q++)
#pragma unroll
                for (int p = 0; p < 4; p++)
                    acc[q][p] = fmaf(av[q], wv[p], acc[q][p]);
        }
    }
#pragma unroll
    for (int q = 0; q < 4; q++) {
        int r = r0 + ty * 4 + q;
#pragma unroll
        for (int p = 0; p < 4; p++) {
            int c = c0 + tx * 4 + p;
            float v = acc[q][p];
            if (bias) v += bias[c];
            if (addsrc) v += addsrc[(size_t)r * 256 + c];
            if (act) v = gelu_f(v);
            Cm[(size_t)r * 256 + c] = v;
        }
    }
}

// Partial att-apply: P[b,i,h*32+k] = sum_{j in half} e(m[i,j]) * V2[b,j,h*32+k]
// e = (m<=thr_i) * exp(-scale_h*(m - mmin_i))
// grid: (head*32 + itile, jsplit), 256 threads, TI=64 rows, acc 4x8/thread.
// Es stored [ii][jj] (no transpose scatter); V cols split {4tx, 64+4tx};
// register prefetch of next tile's m/V hides global latency under FMAs.
__global__ __launch_bounds__(256, 2) void k_attapply3(
    const float* __restrict__ m, const float* __restrict__ v2,
    const float* __restrict__ sc, const float* __restrict__ thr,
    const float* __restrict__ mmin, float* __restrict__ P0, float* __restrict__ P1)
{
    __shared__ float Es[64 * 68];    // [ii][jj], stride 68
    __shared__ float Vs[64 * 128];   // [jj][col]
    const int head = blockIdx.x >> 5;
    const int i0 = (blockIdx.x & 31) * 64;
    const int jbase = blockIdx.y * (NN / 2);
    float* __restrict__ P = blockIdx.y ? P1 : P0;
    const int t = threadIdx.x;            // 0..255
    const int tx = t & 15, ty = t >> 4;   // ty 0..15
    const int txv = t & 31, tyv = t >> 5; // for V staging
    const float scale = sc[head];
    const int bbv = txv >> 3, kkv = (txv & 7) * 4;   // V stage column decode

    // rows this thread stages AND computes: ii = q*16 + ty
    float thr_r[4], mmn_r[4];
#pragma unroll
    for (int q = 0; q < 4; q++) {
        thr_r[q] = thr[i0 + q * 16 + ty];
        mmn_r[q] = mmin[i0 + q * 16 + ty];
    }

    float acc[4][8];
#pragma unroll
    for (int q = 0; q < 4; q++)
#pragma unroll
        for (int p = 0; p < 8; p++) acc[q][p] = 0.f;

    f4 pm[4], pv[8];
    const int NT = (NN / 2) / TJ;   // 16

#define LOAD_TILE(S)                                                           \
    do {                                                                       \
        const int j0 = jbase + (S) * TJ;                                       \
        _Pragma("unroll")                                                      \
        for (int q = 0; q < 4; q++)                                            \
            pm[q] = *(const f4*)&m[(size_t)(i0 + q * 16 + ty) * NN + j0 + 4 * tx]; \
        _Pragma("unroll")                                                      \
        for (int l = 0; l < 8; l++) {                                          \
            const int jj = l * 8 + tyv;                                        \
            pv[l] = *(const f4*)&v2[(((size_t)bbv * NN) + j0 + jj) * HIDDEN + head * VD + kkv]; \
        }                                                                      \
    } while (0)

#define STORE_TILE()                                                           \
    do {                                                                       \
        _Pragma("unroll")                                                      \
        for (int q = 0; q < 4; q++) {                                          \
            f4 ev;                                                             \
            _Pragma("unroll")                                                  \
            for (int d = 0; d < 4; d++) {                                      \
                float e = 0.f;                                                 \
                if (pm[q][d] <= thr_r[q]) e = expf(-scale * (pm[q][d] - mmn_r[q])); \
                ev[d] = e;                                                     \
            }                                                                  \
            *(f4*)&Es[(q * 16 + ty) * 68 + 4 * tx] = ev;                       \
        }                                                                      \
        _Pragma("unroll")                                                      \
        for (int l = 0; l < 8; l++)                                            \
            *(f4*)&Vs[(l * 8 + tyv) * 128 + 4 * txv] = pv[l];                  \
    } while (0)

    LOAD_TILE(0);
    STORE_TILE();
    __syncthreads();

    for (int s = 0; s < NT; s++) {
        if (s + 1 < NT) LOAD_TILE(s + 1);
        // compute current tile from LDS
        for (int jc = 0; jc < TJ; jc += 4) {
            f4 ev[4], va[4], vb[4];
#pragma unroll
            for (int q = 0; q < 4; q++)
                ev[q] = *(const f4*)&Es[(q * 16 + ty) * 68 + jc];
#pragma unroll
            for (int d = 0; d < 4; d++) {
                va[d] = *(const f4*)&Vs[(jc + d) * 128 + 4 * tx];
                vb[d] = *(const f4*)&Vs[(jc + d) * 128 + 64 + 4 * tx];
            }
#pragma unroll
            for (int d = 0; d < 4; d++) {
#pragma unroll
                for (int q = 0; q < 4; q++) {
                    const float e = ev[q][d];
#pragma unroll
                    for (int p = 0; p < 4; p++) {
                        acc[q][p]     = fmaf(e, va[d][p], acc[q][p]);
                        acc[q][p + 4] = fmaf(e, vb[d][p], acc[q][p + 4]);
                    }
                }
            }
        }
        if (s + 1 < NT) {
            __syncthreads();
            STORE_TILE();
            __syncthreads();
        }
    }
#undef LOAD_TILE
#undef STORE_TILE

    // epilogue: raw partial sums (invD/gelu applied in combine)
    const int bba = tx >> 3, kka = (tx & 7) * 4;   // cols 4tx   -> b=bba,   k=kka
#pragma unroll
    for (int q = 0; q < 4; q++) {
        const int gi = i0 + q * 16 + ty;
        f4 sa, sb;
#pragma unroll
        for (int p = 0; p < 4; p++) { sa[p] = acc[q][p]; sb[p] = acc[q][p + 4]; }
        *(f4*)&P[(((size_t)bba * NN) + gi) * HIDDEN + head * VD + kka] = sa;
        *(f4*)&P[(((size_t)(bba + 2) * NN) + gi) * HIDDEN + head * VD + kka] = sb;
    }
}

// io[idx] = gelu((io[idx] + p1[idx]) * invD[h,i])
__global__ __launch_bounds__(256) void k_attcombine(const float* __restrict__ p1,
        const float* __restrict__ invD, float* __restrict__ io)
{
    int gid = blockIdx.x * 256 + threadIdx.x;
    int idx = gid * 4;
    int hid = idx & (HIDDEN - 1);
    int i = (idx >> 8) & (NN - 1);
    float sD = invD[(hid >> 5) * NN + i];
    f4 a = *(const f4*)&io[idx];
    f4 b = *(const f4*)&p1[idx];
    f4 r;
#pragma unroll
    for (int k = 0; k < 4; k++) r[k] = gelu_f((a[k] + b[k]) * sD);
    *(f4*)&io[idx] = r;
}

// out[row] = sum_c A[row,c]*w[c] + b   (one wave per row)
__global__ void k_decode(const float* __restrict__ a, const float* __restrict__ w,
                         const float* __restrict__ b, float* __restrict__ out) {
    int gid = blockIdx.x * 256 + threadIdx.x;
    int row = gid >> 6, lane = threadIdx.x & 63;
    const float* ar = a + (size_t)row * HIDDEN;
    float s = ar[lane] * w[lane] + ar[lane + 64] * w[lane + 64]
            + ar[lane + 128] * w[lane + 128] + ar[lane + 192] * w[lane + 192];
    for (int off = 32; off > 0; off >>= 1) s += __shfl_down(s, off);
    if (lane == 0) out[row] = s + b[0];
}

extern "C" void kernel_launch(void* const* d_in, const int* in_sizes, int n_in,
                              void* d_out, int out_size, void* d_ws, size_t ws_size,
                              hipStream_t stream)
{
    (void)in_sizes; (void)n_in; (void)out_size; (void)ws_size;
    const float* x      = (const float*)d_in[0];
    const float* m0     = (const float*)d_in[1];
    const float* m1     = (const float*)d_in[2];
    const float* m2     = (const float*)d_in[3];
    const float* m3     = (const float*)d_in[4];
    const float* en_w   = (const float*)d_in[5];
    const float* en_b   = (const float*)d_in[6];
    const float* down_r = (const float*)d_in[7];
    const float* down_w = (const float*)d_in[8];
    const float* pa0_r  = (const float*)d_in[9];
    const float* pa0_w  = (const float*)d_in[10];
    const float* pa1_r  = (const float*)d_in[11];
    const float* pa1_w  = (const float*)d_in[12];
    const float* mlp0_w1= (const float*)d_in[13];
    const float* mlp0_b1= (const float*)d_in[14];
    const float* mlp0_w2= (const float*)d_in[15];
    const float* mlp0_b2= (const float*)d_in[16];
    const float* w0_w   = (const float*)d_in[17];
    const float* w0_b   = (const float*)d_in[18];
    const float* mlp1_w1= (const float*)d_in[19];
    const float* mlp1_b1= (const float*)d_in[20];
    const float* mlp1_w2= (const float*)d_in[21];
    const float* mlp1_b2= (const float*)d_in[22];
    const float* w1_w   = (const float*)d_in[23];
    const float* w1_b   = (const float*)d_in[24];
    const float* up_r   = (const float*)d_in[25];
    const float* up_w   = (const float*)d_in[26];
    const float* de1_w  = (const float*)d_in[27];
    const float* de1_b  = (const float*)d_in[28];
    const float* de2_w  = (const float*)d_in[29];
    const float* de2_b  = (const float*)d_in[30];
    float* out = (float*)d_out;

    float* WS = (float*)d_ws;
    const size_t SZ = (size_t)NB * NN * HIDDEN;
    float* Hb  = WS;
    float* Ab  = Hb + SZ;
    float* Vb  = Ab + SZ;
    float* T1  = Vb + SZ;
    float* W2T = T1 + SZ;       // 65536
    float* SC  = W2T + 65536;   // 16
    float* THR = SC + 16;       // 2048
    float* MMIN= THR + NN;      // 2048
    float* INVD= MMIN + NN;     // H*N
    float* T3  = Vb;            // alias: value buffer dead outside posatt

    auto posatt = [&](const float* src, float* dst2, const float* md,
                      const float* r, const float* w, int kc) {
        hipLaunchKernelGGL(k_scales, dim3(1), dim3(64), 0, stream, r, SC);
        hipLaunchKernelGGL(k_thrsel, dim3(NN), dim3(256), 0, stream, md, SC, THR, MMIN, INVD, kc);
        hipLaunchKernelGGL(k_wt, dim3(256), dim3(256), 0, stream, w, W2T);
        hipLaunchKernelGGL(k_gemm, dim3(128, 4), dim3(256), 0, stream,
                           src, W2T, (const float*)nullptr, (const float*)nullptr, Vb, 0);
        // partial sums: split 0 -> dst2, split 1 -> T1 (both free here)
        hipLaunchKernelGGL(k_attapply3, dim3(256, 2), dim3(256), 0, stream,
                           md, Vb, SC, THR, MMIN, dst2, T1);
        hipLaunchKernelGGL(k_attcombine, dim3((int)(SZ / 4 / 256)), dim3(256), 0, stream,
                           T1, INVD, dst2);
    };

    float* curH = Hb; float* oth = Ab;
    hipLaunchKernelGGL(k_encode, dim3(8192), dim3(256), 0, stream, x, en_w, en_b, curH);

    // down: locality 50 -> k=1024
    posatt(curH, oth, m0, down_r, down_w, 1024);
    { float* tmp = curH; curH = oth; oth = tmp; }

    // block 0: PA uses locality 50 -> k=1024
    posatt(curH, oth, m1, pa0_r, pa0_w, 1024);
    hipLaunchKernelGGL(k_gemm, dim3(128, 4), dim3(256), 0, stream,
                       curH, w0_w, w0_b, (const float*)nullptr, T3, 0);
    hipLaunchKernelGGL(k_gemm, dim3(128, 4), dim3(256), 0, stream,
                       oth, mlp0_w1, mlp0_b1, (const float*)nullptr, T1, 1);
    hipLaunchKernelGGL(k_gemm, dim3(128, 4), dim3(256), 0, stream,
                       T1, mlp0_w2, mlp0_b2, (const float*)T3, oth, 1);
    { float* tmp = curH; curH = oth; oth = tmp; }

    // block 1: PA uses locality 30 -> k=615
    posatt(curH, oth, m2, pa1_r, pa1_w, 615);
    hipLaunchKernelGGL(k_gemm, dim3(128, 4), dim3(256), 0, stream,
                       curH, w1_w, w1_b, (const float*)nullptr, T3, 0);
    hipLaunchKernelGGL(k_gemm, dim3(128, 4), dim3(256), 0, stream,
                       oth, mlp1_w1, mlp1_b1, (const float*)nullptr, T1, 1);
    hipLaunchKernelGGL(k_gemm, dim3(128, 4), dim3(256), 0, stream,
                       T1, mlp1_w2, mlp1_b2, (const float*)T3, oth, 1);
    { float* tmp = curH; curH = oth; oth = tmp; }

    // up: locality 80 -> k=1638
    posatt(curH, oth, m3, up_r, up_w, 1638);
    { float* tmp = curH; curH = oth; oth = tmp; }

    hipLaunchKernelGGL(k_gemm, dim3(128, 4), dim3(256), 0, stream,
                       curH, de1_w, de1_b, (const float*)nullptr, T1, 1);
    hipLaunchKernelGGL(k_decode, dim3(2048), dim3(256), 0, stream, T1, de2_w, de2_b, out);
}

// Round 4
// 1079.566 us; speedup vs baseline: 2.5622x; 1.0561x over previous
//
#include <hip/hip_runtime.h>

#define NB 4
#define NN 2048
#define HIDDEN 256
#define NH 8
#define VD 32
#define TJ 64

typedef float f4 __attribute__((ext_vector_type(4)));

__device__ __forceinline__ float gelu_f(float v) {
    return 0.5f * v * (1.0f + erff(v * 0.7071067811865475f));
}

// h[b,n,c] = gelu(sum_i x[b,n,i]*w[i,c] + b[c]),  IN_C=3
__global__ void k_encode(const float* __restrict__ x, const float* __restrict__ w,
                         const float* __restrict__ b, float* __restrict__ out) {
    int id = blockIdx.x * 256 + threadIdx.x;
    int c = id & 255, rn = id >> 8;
    float acc = b[c];
    acc += x[rn * 3 + 0] * w[c] + x[rn * 3 + 1] * w[256 + c] + x[rn * 3 + 2] * w[512 + c];
    out[id] = gelu_f(acc);
}

// Per row of m: k-th smallest (radix select), row min, per-head softmax denom.
// Wave-level scans/reductions: ~22 barriers total (was ~80).
__global__ __launch_bounds__(256) void k_thrsel(const float* __restrict__ m,
        const float* __restrict__ rv, float* __restrict__ thr,
        float* __restrict__ mmin, float* __restrict__ invD, int kcount)
{
    __shared__ float rowf[NN];
    __shared__ unsigned hist[256];
    __shared__ float redf[32];
    __shared__ unsigned redu[4];
    __shared__ unsigned s_bin, s_below;
    const int row = blockIdx.x, t = threadIdx.x;
    const int lane = t & 63, wid = t >> 6;
    const float* mr = m + (size_t)row * NN;

    float lmin = 3.4e38f;
    for (int i = t; i < NN; i += 256) { float v = mr[i]; rowf[i] = v; lmin = fminf(lmin, v); }
#pragma unroll
    for (int d = 32; d > 0; d >>= 1) lmin = fminf(lmin, __shfl_xor(lmin, d, 64));
    if (lane == 0) redf[wid] = lmin;
    __syncthreads();
    const float rmin = fminf(fminf(redf[0], redf[1]), fminf(redf[2], redf[3]));

    // radix select k-th smallest on order-preserving uint transform
    unsigned prefix = 0; int want = kcount;
    const unsigned hmasks[4] = {0u, 0xFF000000u, 0xFFFF0000u, 0xFFFFFF00u};
    for (int pass = 0; pass < 4; ++pass) {
        const int shift = 24 - 8 * pass;
        hist[t] = 0;
        __syncthreads();
        const unsigned hm = hmasks[pass];
        for (int i = t; i < NN; i += 256) {
            unsigned u = __float_as_uint(rowf[i]);
            u ^= (u & 0x80000000u) ? 0xFFFFFFFFu : 0x80000000u;
            if ((u & hm) == (prefix & hm))
                atomicAdd(&hist[(u >> shift) & 255u], 1u);
        }
        __syncthreads();
        const unsigned cnt = hist[t];
        unsigned v = cnt;
#pragma unroll
        for (int d = 1; d < 64; d <<= 1) {
            unsigned o = __shfl_up(v, d, 64);
            if (lane >= d) v += o;
        }
        if (lane == 63) redu[wid] = v;
        __syncthreads();
        unsigned woff = 0;
#pragma unroll
        for (int w = 0; w < 3; w++) if (w < wid) woff += redu[w];
        const unsigned incl = v + woff;
        const unsigned below = incl - cnt;
        if (incl >= (unsigned)want && below < (unsigned)want) { s_bin = (unsigned)t; s_below = below; }
        __syncthreads();
        want -= (int)s_below;
        prefix |= (s_bin << shift);
    }
    unsigned ku = prefix;
    ku = (ku & 0x80000000u) ? (ku & 0x7FFFFFFFu) : ~ku;
    const float tf = __uint_as_float(ku);

    const float cc = (float)(0.25 * 3.141592653589793 * (1.0 - 1e-7));
    float sch[NH], lacc[NH];
#pragma unroll
    for (int h = 0; h < NH; h++) { sch[h] = tanf(cc * (1.0f + sinf(rv[h]))); lacc[h] = 0.f; }
    for (int i = t; i < NN; i += 256) {
        float v = rowf[i];
        if (v <= tf) {
            float d = v - rmin;
#pragma unroll
            for (int h = 0; h < NH; h++) lacc[h] += expf(-sch[h] * d);
        }
    }
#pragma unroll
    for (int h = 0; h < NH; h++) {
#pragma unroll
        for (int d = 32; d > 0; d >>= 1) lacc[h] += __shfl_xor(lacc[h], d, 64);
    }
    if (lane == 0) {
#pragma unroll
        for (int h = 0; h < NH; h++) redf[wid * 8 + h] = lacc[h];
    }
    __syncthreads();
    if (t < NH)
        invD[t * NN + row] = 1.0f / (redf[t] + redf[8 + t] + redf[16 + t] + redf[24 + t]);
    if (t == 0) { thr[row] = tf; mmin[row] = rmin; }
}

// C[r,c] = act( A[r,:]@W[:,c] + bias[c] + add[r,c] )   M=8192, K=256, Ncol=256
// wmode=1: W is pos-att weights [H][HID][VD], col=(h*32+v)  (transpose folded in)
__global__ __launch_bounds__(256) void k_gemm(const float* __restrict__ A,
        const float* __restrict__ Wm, const float* __restrict__ bias,
        const float* __restrict__ addsrc, float* __restrict__ Cm, int act, int wmode)
{
    __shared__ float AsT[64 * 68];  // [kk][row], padded
    __shared__ float Ws[64 * 68];   // [kk][col], padded
    const int r0 = blockIdx.x * 64;
    const int c0 = blockIdx.y * 64;
    const int t = threadIdx.x;
    const int ty = t >> 4, tx = t & 15;
    float acc[4][4] = {};
    for (int k0 = 0; k0 < 256; k0 += 64) {
        __syncthreads();
#pragma unroll
        for (int l = 0; l < 16; l++) {
            int lin = l * 256 + t;
            int rr = lin >> 6, kk = lin & 63;
            AsT[kk * 68 + rr] = A[(size_t)(r0 + rr) * 256 + k0 + kk];
            Ws[rr * 68 + kk] = wmode
                ? Wm[(size_t)((c0 + kk) >> 5) * (HIDDEN * VD) + (size_t)(k0 + rr) * VD + ((c0 + kk) & 31)]
                : Wm[(size_t)(k0 + rr) * 256 + c0 + kk];
        }
        __syncthreads();
#pragma unroll 8
        for (int kk = 0; kk < 64; kk++) {
            const float4 a4 = *(const float4*)&AsT[kk * 68 + ty * 4];
            const float4 w4 = *(const float4*)&Ws[kk * 68 + tx * 4];
            float av[4] = {a4.x, a4.y, a4.z, a4.w};
            float wv[4] = {w4.x, w4.y, w4.z, w4.w};
#pragma unroll
            for (int q = 0; q < 4; q++)
#pragma unroll
                for (int p = 0; p < 4; p++)
                    acc[q][p] = fmaf(av[q], wv[p], acc[q][p]);
        }
    }
#pragma unroll
    for (int q = 0; q < 4; q++) {
        int r = r0 + ty * 4 + q;
#pragma unroll
        for (int p = 0; p < 4; p++) {
            int c = c0 + tx * 4 + p;
            float v = acc[q][p];
            if (bias) v += bias[c];
            if (addsrc) v += addsrc[(size_t)r * 256 + c];
            if (act) v = gelu_f(v);
            Cm[(size_t)r * 256 + c] = v;
        }
    }
}

// Partial att-apply: P[b,i,h*32+k] = sum_{j in split} e(m[i,j]) * V2[b,j,h*32+k]
// e = (m<=thr_i) * exp(-scale_h*(m - mmin_i))
// grid: (head*16 + itile, jsplit), 256 threads, i-tile=128, acc 8x8/thread.
// LDS = 64 KB exactly (Es[128][64] + Vs[64][128]) -> 2 blocks/CU.
__global__ __launch_bounds__(256, 2) void k_attapply4(
    const float* __restrict__ m, const float* __restrict__ v2,
    const float* __restrict__ rv, const float* __restrict__ thr,
    const float* __restrict__ mmin,
    float* __restrict__ P0, float* __restrict__ P1,
    float* __restrict__ P2, float* __restrict__ P3, int jlen)
{
    __shared__ float Es[128 * 64];   // [ii][jj]
    __shared__ float Vs[64 * 128];   // [jj][col]
    const int head = blockIdx.x >> 4;
    const int i0 = (blockIdx.x & 15) * 128;
    const int jbase = blockIdx.y * jlen;
    float* __restrict__ P = (blockIdx.y == 0) ? P0 : (blockIdx.y == 1) ? P1
                          : (blockIdx.y == 2) ? P2 : P3;
    const int t = threadIdx.x;            // 0..255
    const int tx = t & 15, ty = t >> 4;   // cols {4tx,64+4tx}, rows q*16+ty
    const int txv = t & 31, tyv = t >> 5; // V staging
    const int bbv = txv >> 3, kkv = (txv & 7) * 4;
    const float cc = (float)(0.25 * 3.141592653589793 * (1.0 - 1e-7));
    const float scale = tanf(cc * (1.0f + sinf(rv[head])));

    float thr_r[8], mmn_r[8];
#pragma unroll
    for (int q = 0; q < 8; q++) {
        thr_r[q] = thr[i0 + q * 16 + ty];
        mmn_r[q] = mmin[i0 + q * 16 + ty];
    }

    float acc[8][8];
#pragma unroll
    for (int q = 0; q < 8; q++)
#pragma unroll
        for (int p = 0; p < 8; p++) acc[q][p] = 0.f;

    f4 pm[8], pv[8];
    const int NT = jlen / TJ;

#define LOAD_TILE(S)                                                           \
    do {                                                                       \
        const int j0 = jbase + (S) * TJ;                                       \
        _Pragma("unroll")                                                      \
        for (int q = 0; q < 8; q++)                                            \
            pm[q] = *(const f4*)&m[(size_t)(i0 + q * 16 + ty) * NN + j0 + 4 * tx]; \
        _Pragma("unroll")                                                      \
        for (int l = 0; l < 8; l++)                                            \
            pv[l] = *(const f4*)&v2[(((size_t)bbv * NN) + j0 + l * 8 + tyv) * HIDDEN + head * VD + kkv]; \
    } while (0)

#define STORE_TILE()                                                           \
    do {                                                                       \
        _Pragma("unroll")                                                      \
        for (int q = 0; q < 8; q++) {                                          \
            f4 ev;                                                             \
            _Pragma("unroll")                                                  \
            for (int d = 0; d < 4; d++) {                                      \
                float e = 0.f;                                                 \
                if (pm[q][d] <= thr_r[q]) e = expf(-scale * (pm[q][d] - mmn_r[q])); \
                ev[d] = e;                                                     \
            }                                                                  \
            *(f4*)&Es[(q * 16 + ty) * 64 + 4 * tx] = ev;                       \
        }                                                                      \
        _Pragma("unroll")                                                      \
        for (int l = 0; l < 8; l++)                                            \
            *(f4*)&Vs[(l * 8 + tyv) * 128 + 4 * txv] = pv[l];                  \
    } while (0)

    LOAD_TILE(0);
    STORE_TILE();
    __syncthreads();

    for (int s = 0; s < NT; s++) {
        if (s + 1 < NT) LOAD_TILE(s + 1);
        for (int jc = 0; jc < TJ; jc += 4) {
            f4 ev[8], va[4], vb[4];
#pragma unroll
            for (int q = 0; q < 8; q++)
                ev[q] = *(const f4*)&Es[(q * 16 + ty) * 64 + jc];
#pragma unroll
            for (int d = 0; d < 4; d++) {
                va[d] = *(const f4*)&Vs[(jc + d) * 128 + 4 * tx];
                vb[d] = *(const f4*)&Vs[(jc + d) * 128 + 64 + 4 * tx];
            }
#pragma unroll
            for (int d = 0; d < 4; d++) {
#pragma unroll
                for (int q = 0; q < 8; q++) {
                    const float e = ev[q][d];
#pragma unroll
                    for (int p = 0; p < 4; p++) {
                        acc[q][p]     = fmaf(e, va[d][p], acc[q][p]);
                        acc[q][p + 4] = fmaf(e, vb[d][p], acc[q][p + 4]);
                    }
                }
            }
        }
        if (s + 1 < NT) {
            __syncthreads();
            STORE_TILE();
            __syncthreads();
        }
    }
#undef LOAD_TILE
#undef STORE_TILE

    // epilogue: raw partial sums (invD/gelu applied in combine)
    const int bba = tx >> 3, kka = (tx & 7) * 4;
#pragma unroll
    for (int q = 0; q < 8; q++) {
        const int gi = i0 + q * 16 + ty;
        f4 sa, sb;
#pragma unroll
        for (int p = 0; p < 4; p++) { sa[p] = acc[q][p]; sb[p] = acc[q][p + 4]; }
        *(f4*)&P[(((size_t)bba * NN) + gi) * HIDDEN + head * VD + kka] = sa;
        *(f4*)&P[(((size_t)(bba + 2) * NN) + gi) * HIDDEN + head * VD + kka] = sb;
    }
}

// io = gelu((io + p1 [+ p2 + p3]) * invD[h,i])
__global__ __launch_bounds__(256) void k_attcombine(const float* __restrict__ p1,
        const float* __restrict__ p2, const float* __restrict__ p3,
        const float* __restrict__ invD, float* __restrict__ io)
{
    int gid = blockIdx.x * 256 + threadIdx.x;
    int idx = gid * 4;
    int hid = idx & (HIDDEN - 1);
    int i = (idx >> 8) & (NN - 1);
    float sD = invD[(hid >> 5) * NN + i];
    f4 a = *(const f4*)&io[idx];
    f4 b = *(const f4*)&p1[idx];
    f4 s;
#pragma unroll
    for (int k = 0; k < 4; k++) s[k] = a[k] + b[k];
    if (p2) {
        f4 c = *(const f4*)&p2[idx];
        f4 d = *(const f4*)&p3[idx];
#pragma unroll
        for (int k = 0; k < 4; k++) s[k] += c[k] + d[k];
    }
#pragma unroll
    for (int k = 0; k < 4; k++) s[k] = gelu_f(s[k] * sD);
    *(f4*)&io[idx] = s;
}

// out[row] = sum_c A[row,c]*w[c] + b   (one wave per row)
__global__ void k_decode(const float* __restrict__ a, const float* __restrict__ w,
                         const float* __restrict__ b, float* __restrict__ out) {
    int gid = blockIdx.x * 256 + threadIdx.x;
    int row = gid >> 6, lane = threadIdx.x & 63;
    const float* ar = a + (size_t)row * HIDDEN;
    float s = ar[lane] * w[lane] + ar[lane + 64] * w[lane + 64]
            + ar[lane + 128] * w[lane + 128] + ar[lane + 192] * w[lane + 192];
    for (int off = 32; off > 0; off >>= 1) s += __shfl_down(s, off);
    if (lane == 0) out[row] = s + b[0];
}

extern "C" void kernel_launch(void* const* d_in, const int* in_sizes, int n_in,
                              void* d_out, int out_size, void* d_ws, size_t ws_size,
                              hipStream_t stream)
{
    (void)in_sizes; (void)n_in; (void)out_size;
    const float* x      = (const float*)d_in[0];
    const float* m0     = (const float*)d_in[1];
    const float* m1     = (const float*)d_in[2];
    const float* m2     = (const float*)d_in[3];
    const float* m3     = (const float*)d_in[4];
    const float* en_w   = (const float*)d_in[5];
    const float* en_b   = (const float*)d_in[6];
    const float* down_r = (const float*)d_in[7];
    const float* down_w = (const float*)d_in[8];
    const float* pa0_r  = (const float*)d_in[9];
    const float* pa0_w  = (const float*)d_in[10];
    const float* pa1_r  = (const float*)d_in[11];
    const float* pa1_w  = (const float*)d_in[12];
    const float* mlp0_w1= (const float*)d_in[13];
    const float* mlp0_b1= (const float*)d_in[14];
    const float* mlp0_w2= (const float*)d_in[15];
    const float* mlp0_b2= (const float*)d_in[16];
    const float* w0_w   = (const float*)d_in[17];
    const float* w0_b   = (const float*)d_in[18];
    const float* mlp1_w1= (const float*)d_in[19];
    const float* mlp1_b1= (const float*)d_in[20];
    const float* mlp1_w2= (const float*)d_in[21];
    const float* mlp1_b2= (const float*)d_in[22];
    const float* w1_w   = (const float*)d_in[23];
    const float* w1_b   = (const float*)d_in[24];
    const float* up_r   = (const float*)d_in[25];
    const float* up_w   = (const float*)d_in[26];
    const float* de1_w  = (const float*)d_in[27];
    const float* de1_b  = (const float*)d_in[28];
    const float* de2_w  = (const float*)d_in[29];
    const float* de2_b  = (const float*)d_in[30];
    float* out = (float*)d_out;

    float* WS = (float*)d_ws;
    const size_t SZ = (size_t)NB * NN * HIDDEN;
    float* Hb  = WS;
    float* Ab  = Hb + SZ;
    float* Vb  = Ab + SZ;
    float* T1  = Vb + SZ;
    float* THR = T1 + SZ;       // 2048
    float* MMIN= THR + NN;      // 2048
    float* INVD= MMIN + NN;     // H*N
    float* P2  = INVD + NH * NN;
    float* P3  = P2 + SZ;
    const size_t need4 = (size_t)((P3 + SZ) - WS) * sizeof(float);
    const int JS = (ws_size >= need4) ? 4 : 2;   // j-split factor
    float* T3  = Vb;            // alias: value buffer dead outside posatt

    auto posatt = [&](const float* src, float* dst2, const float* md,
                      const float* r, const float* w, int kc) {
        hipLaunchKernelGGL(k_thrsel, dim3(NN), dim3(256), 0, stream, md, r, THR, MMIN, INVD, kc);
        hipLaunchKernelGGL(k_gemm, dim3(128, 4), dim3(256), 0, stream,
                           src, w, (const float*)nullptr, (const float*)nullptr, Vb, 0, 1);
        hipLaunchKernelGGL(k_attapply4, dim3(128, JS), dim3(256), 0, stream,
                           md, Vb, r, THR, MMIN, dst2, T1, P2, P3, NN / JS);
        hipLaunchKernelGGL(k_attcombine, dim3((int)(SZ / 4 / 256)), dim3(256), 0, stream,
                           T1, (JS == 4) ? P2 : (const float*)nullptr,
                           (JS == 4) ? P3 : (const float*)nullptr, INVD, dst2);
    };

    float* curH = Hb; float* oth = Ab;
    hipLaunchKernelGGL(k_encode, dim3(8192), dim3(256), 0, stream, x, en_w, en_b, curH);

    // down: locality 50 -> k=1024
    posatt(curH, oth, m0, down_r, down_w, 1024);
    { float* tmp = curH; curH = oth; oth = tmp; }

    // block 0: PA uses locality 50 -> k=1024
    posatt(curH, oth, m1, pa0_r, pa0_w, 1024);
    hipLaunchKernelGGL(k_gemm, dim3(128, 4), dim3(256), 0, stream,
                       curH, w0_w, w0_b, (const float*)nullptr, T3, 0, 0);
    hipLaunchKernelGGL(k_gemm, dim3(128, 4), dim3(256), 0, stream,
                       oth, mlp0_w1, mlp0_b1, (const float*)nullptr, T1, 1, 0);
    hipLaunchKernelGGL(k_gemm, dim3(128, 4), dim3(256), 0, stream,
                       T1, mlp0_w2, mlp0_b2, (const float*)T3, oth, 1, 0);
    { float* tmp = curH; curH = oth; oth = tmp; }

    // block 1: PA uses locality 30 -> k=615
    posatt(curH, oth, m2, pa1_r, pa1_w, 615);
    hipLaunchKernelGGL(k_gemm, dim3(128, 4), dim3(256), 0, stream,
                       curH, w1_w, w1_b, (const float*)nullptr, T3, 0, 0);
    hipLaunchKernelGGL(k_gemm, dim3(128, 4), dim3(256), 0, stream,
                       oth, mlp1_w1, mlp1_b1, (const float*)nullptr, T1, 1, 0);
    hipLaunchKernelGGL(k_gemm, dim3(128, 4), dim3(256), 0, stream,
                       T1, mlp1_w2, mlp1_b2, (const float*)T3, oth, 1, 0);
    { float* tmp = curH; curH = oth; oth = tmp; }

    // up: locality 80 -> k=1638
    posatt(curH, oth, m3, up_r, up_w, 1638);
    { float* tmp = curH; curH = oth; oth = tmp; }

    hipLaunchKernelGGL(k_gemm, dim3(128, 4), dim3(256), 0, stream,
                       curH, de1_w, de1_b, (const float*)nullptr, T1, 1, 0);
    hipLaunchKernelGGL(k_decode, dim3(2048), dim3(256), 0, stream, T1, de2_w, de2_b, out);
}